// Round 1
// 670.882 us; speedup vs baseline: 1.0063x; 1.0063x over previous
//
#include <hip/hip_runtime.h>

// Problem constants (from setup_inputs):
//   x: [4096,1] f32, edge_index: [2,131072] delivered as int32, W1: [1,8] f32,
//   b1: [8] f32, Wr: [32768,4096] f32 (512 MB -- the whole cost), br: [4096] f32
//   out: [4096] f32
#define N_NODES 4096
#define HID 8
#define N_EDGES 131072
#define YDIM 4096
#define K_TOT (N_NODES * HID)   // 32768
#define KC 128                  // K-chunk per gemv block
#define GEMV_BLOCK 256

// ---- K1: init deg (self-loop = 1), t accumulator, and out = br ----
__global__ __launch_bounds__(256) void k_init(float* __restrict__ deg,
                                              float* __restrict__ t,
                                              float* __restrict__ out,
                                              const float* __restrict__ br) {
  int i = blockIdx.x * blockDim.x + threadIdx.x;
  if (i < N_NODES) { deg[i] = 1.0f; t[i] = 0.0f; }
  if (i < YDIM) out[i] = br[i];
}

// ---- K2: degree count over dst. 2 edges/thread via int2 (N_EDGES is even) ----
__global__ __launch_bounds__(256) void k_deg(const int* __restrict__ ei,
                                             float* __restrict__ deg) {
  int e = (blockIdx.x * blockDim.x + threadIdx.x) * 2;
  if (e < N_EDGES) {
    int2 d = *(const int2*)(ei + N_EDGES + e);   // edge_index[1] = dst
    atomicAdd(&deg[d.x], 1.0f);
    atomicAdd(&deg[d.y], 1.0f);
  }
}

// ---- K3: dinv = rsqrt(deg) (deg >= 1 always); also xd = x*dinv so the
//      scatter kernel does ONE gather per edge instead of two ----
__global__ __launch_bounds__(256) void k_dinv(const float* __restrict__ deg,
                                              const float* __restrict__ x,
                                              float* __restrict__ dinv,
                                              float* __restrict__ xd) {
  int i = blockIdx.x * blockDim.x + threadIdx.x;
  if (i < N_NODES) {
    float di = rsqrtf(deg[i]);
    dinv[i] = di;
    xd[i] = x[i] * di;
  }
}

// ---- K4: message scatter: t[dst] += xd[src]. 2 edges/thread ----
__global__ __launch_bounds__(256) void k_scatter(const int* __restrict__ ei,
                                                 const float* __restrict__ xd,
                                                 float* __restrict__ t) {
  int e = (blockIdx.x * blockDim.x + threadIdx.x) * 2;
  if (e < N_EDGES) {
    int2 s = *(const int2*)(ei + e);             // edge_index[0] = src
    int2 d = *(const int2*)(ei + N_EDGES + e);   // edge_index[1] = dst
    atomicAdd(&t[d.x], xd[s.x]);
    atomicAdd(&t[d.y], xd[s.y]);
  }
}

// ---- K5: h[i*8+j] = relu( dinv[i]*(t[i] + x[i]*dinv[i]) * W1[j] + b1[j] ) ----
__global__ __launch_bounds__(256) void k_h(const float* __restrict__ xd,
                                           const float* __restrict__ dinv,
                                           const float* __restrict__ t,
                                           const float* __restrict__ W1,
                                           const float* __restrict__ b1,
                                           float* __restrict__ h) {
  int i = blockIdx.x * blockDim.x + threadIdx.x;
  if (i < N_NODES) {
    float di = dinv[i];
    float s = di * (t[i] + xd[i]);   // xd[i] == x[i]*dinv[i]
#pragma unroll
    for (int j = 0; j < HID; ++j) {
      float v = s * W1[j] + b1[j];
      h[i * HID + j] = v > 0.0f ? v : 0.0f;
    }
  }
}

// ---- K6: split-K GEMV  y[j] += sum_k h[k] * Wr[k, j] ----
// grid = 4 column-groups x (K_TOT/KC) chunks, 4 blocks/CU (16 waves/CU).
// Compaction of nonzero h (relu kills ~50% of rows; each skipped row is
// 16 KB of Wr never fetched). Inner loop hand-unrolled x4 so each wave
// keeps >=4 independent 1 KB loads in flight (guards against the compiler
// under-pipelining the ds_read(ks) -> global_load dependent chain).
__global__ __launch_bounds__(GEMV_BLOCK) void k_gemv(const float* __restrict__ Wr,
                                                     const float* __restrict__ h,
                                                     float* __restrict__ out) {
  __shared__ float hs[KC];
  __shared__ int ks[KC];
  __shared__ int cnt;
  const int tid = threadIdx.x;
  const int cg = blockIdx.x & 3;    // column group (4 x 1024 cols)
  const int ck = blockIdx.x >> 2;   // k-chunk
  const int k0 = ck * KC;

  if (tid == 0) cnt = 0;
  __syncthreads();
  if (tid < KC) {
    float v = h[k0 + tid];
    if (v != 0.0f) {
      int p = atomicAdd(&cnt, 1);
      hs[p] = v;
      ks[p] = tid;
    }
  }
  __syncthreads();

  const int n = cnt;
  const int col = cg * (GEMV_BLOCK * 4) + tid * 4;
  const float* base = Wr + (size_t)k0 * YDIM + col;
  float ax = 0.f, ay = 0.f, az = 0.f, aw = 0.f;

  int q = 0;
  for (; q + 4 <= n; q += 4) {
    float h0 = hs[q + 0], h1 = hs[q + 1], h2 = hs[q + 2], h3 = hs[q + 3];
    int   j0 = ks[q + 0], j1 = ks[q + 1], j2 = ks[q + 2], j3 = ks[q + 3];
    const float4 w0 = *(const float4*)(base + (size_t)j0 * YDIM);
    const float4 w1 = *(const float4*)(base + (size_t)j1 * YDIM);
    const float4 w2 = *(const float4*)(base + (size_t)j2 * YDIM);
    const float4 w3 = *(const float4*)(base + (size_t)j3 * YDIM);
    ax += h0 * w0.x; ay += h0 * w0.y; az += h0 * w0.z; aw += h0 * w0.w;
    ax += h1 * w1.x; ay += h1 * w1.y; az += h1 * w1.z; aw += h1 * w1.w;
    ax += h2 * w2.x; ay += h2 * w2.y; az += h2 * w2.z; aw += h2 * w2.w;
    ax += h3 * w3.x; ay += h3 * w3.y; az += h3 * w3.z; aw += h3 * w3.w;
  }
  for (; q < n; ++q) {
    float hv = hs[q];
    int kk = ks[q];
    const float4 w = *(const float4*)(base + (size_t)kk * YDIM);
    ax += hv * w.x; ay += hv * w.y; az += hv * w.z; aw += hv * w.w;
  }

  atomicAdd(&out[col + 0], ax);
  atomicAdd(&out[col + 1], ay);
  atomicAdd(&out[col + 2], az);
  atomicAdd(&out[col + 3], aw);
}

extern "C" void kernel_launch(void* const* d_in, const int* in_sizes, int n_in,
                              void* d_out, int out_size, void* d_ws, size_t ws_size,
                              hipStream_t stream) {
  const float* x  = (const float*)d_in[0];
  const int*   ei = (const int*)d_in[1];     // int inputs delivered as int32
  const float* W1 = (const float*)d_in[2];
  const float* b1 = (const float*)d_in[3];
  const float* Wr = (const float*)d_in[4];
  const float* br = (const float*)d_in[5];
  float* out = (float*)d_out;

  // Workspace layout (fp32): deg[4096] dinv[4096] t[4096] xd[4096] h[32768] ~196 KB
  float* deg  = (float*)d_ws;
  float* dinv = deg + N_NODES;
  float* t    = dinv + N_NODES;
  float* xd   = t + N_NODES;
  float* h    = xd + N_NODES;

  k_init   <<<(N_NODES + 255) / 256, 256, 0, stream>>>(deg, t, out, br);
  k_deg    <<<(N_EDGES / 2 + 255) / 256, 256, 0, stream>>>(ei, deg);
  k_dinv   <<<(N_NODES + 255) / 256, 256, 0, stream>>>(deg, x, dinv, xd);
  k_scatter<<<(N_EDGES / 2 + 255) / 256, 256, 0, stream>>>(ei, xd, t);
  k_h      <<<(N_NODES + 255) / 256, 256, 0, stream>>>(xd, dinv, t, W1, b1, h);
  k_gemv   <<<4 * (K_TOT / KC), GEMV_BLOCK, 0, stream>>>(Wr, h, out);
}